// Round 5
// baseline (821.865 us; speedup 1.0000x reference)
//
#include <hip/hip_runtime.h>

#define S_N 20000
#define E_N 10000
#define K_N 128
#define D_N 128
#define NEK 40000
#define NSE 500000
#define B_N 2048

typedef __attribute__((ext_vector_type(8))) short bf16x8;
typedef __attribute__((ext_vector_type(4))) float f32x4;

__device__ __forceinline__ unsigned short f2bf(float f){
  unsigned int u = __float_as_uint(f);
  unsigned int r = u + 0x7FFFu + ((u >> 16) & 1u);   // RNE to bf16
  return (unsigned short)(r >> 16);
}
__device__ __forceinline__ float bf2f(unsigned short h){
  return __uint_as_float(((unsigned int)h) << 16);
}
__device__ __forceinline__ void cvt8(const float* fa, bf16x8& h8, bf16x8& l8){
  #pragma unroll
  for(int j=0;j<8;j++){
    unsigned short hb = f2bf(fa[j]);
    h8[j] = (short)hb;
    l8[j] = (short)f2bf(fa[j] - bf2f(hb));
  }
}

struct GS { const float* A; const unsigned short* Wh; const unsigned short* Wl;
            const float* wa; float* Z; float* P; int rows; };
struct SSet { const float* z; const float* p; const int* rowptr; const int* col;
              const float* base; float* out; int ndst; };
struct CSet { const int* cnt; int n; int* rp; int* cur; };

// ---- hist (+ wprep piggybacked on trailing 8 blocks) ----
// wprep: per gate, MFMA-lane-layout bf16 hi/lo W fragments + wa = W@a1
#define HB ((NSE+255)/256)
__global__ __launch_bounds__(256) void k_hist(const int* __restrict__ eks, const int* __restrict__ ekd,
      const int* __restrict__ ses, const int* __restrict__ sed,
      int* c_eke, int* c_ekk, int* c_see, int* c_ses,
      const float* __restrict__ GW, const float* __restrict__ Ga,
      unsigned short* __restrict__ wf, float* __restrict__ wa){
  int bb = blockIdx.x;
  if(bb >= HB){
    int g = bb - HB;                         // gate 0..7
    const float* W  = GW + (size_t)g*16384;
    const float* a1 = Ga + (size_t)g*256;    // src-half of attention vector
    unsigned short* whi = wf + (size_t)g*16384;
    unsigned short* wlo = wf + (size_t)(8+g)*16384;
    int t = threadIdx.x, l = t & 63;
    for(int pi = t>>6; pi < 32; pi += 4){
      int c2 = pi >> 2, kt = pi & 3;
      unsigned short h[8], lo[8];
      #pragma unroll
      for(int j=0;j<8;j++){
        int k = kt*32 + (l>>4)*8 + j;
        int c = c2*16 + (l&15);
        float f = W[(size_t)k*128 + c];
        unsigned short hb = f2bf(f);
        h[j] = hb; lo[j] = f2bf(f - bf2f(hb));
      }
      size_t off = ((size_t)pi*64 + l)*8;
      uint4 hv, lv;
      hv.x = (unsigned)h[0] | ((unsigned)h[1]<<16);  hv.y = (unsigned)h[2] | ((unsigned)h[3]<<16);
      hv.z = (unsigned)h[4] | ((unsigned)h[5]<<16);  hv.w = (unsigned)h[6] | ((unsigned)h[7]<<16);
      lv.x = (unsigned)lo[0] | ((unsigned)lo[1]<<16); lv.y = (unsigned)lo[2] | ((unsigned)lo[3]<<16);
      lv.z = (unsigned)lo[4] | ((unsigned)lo[5]<<16); lv.w = (unsigned)lo[6] | ((unsigned)lo[7]<<16);
      *(uint4*)(whi + off) = hv;
      *(uint4*)(wlo + off) = lv;
    }
    for(int k = t; k < 128; k += 256){       // wa[k] = sum_c W[k][c]*a1[c]
      float s = 0.f;
      const float* wr = W + (size_t)k*128;
      for(int c=0;c<128;c++) s += wr[c]*a1[c];
      wa[(size_t)g*128 + k] = s;
    }
    return;
  }
  int i = bb*256 + threadIdx.x;
  if(i < NEK){ atomicAdd(c_eke + eks[i], 1); atomicAdd(c_ekk + (ekd[i]-E_N), 1); }
  if(i < NSE){ atomicAdd(c_see + ses[i], 1); atomicAdd(c_ses + (sed[i]-E_N), 1); }
}

__global__ __launch_bounds__(1024) void k_scan(CSet c0, CSet c1, CSet c2, CSet c3){
  CSet c = c0;
  if(blockIdx.x==1) c=c1; else if(blockIdx.x==2) c=c2; else if(blockIdx.x==3) c=c3;
  __shared__ int part[1024];
  int t = threadIdx.x;
  int n = c.n;
  int chunk = (n + 1023) >> 10;
  int b0 = t * chunk;
  int s = 0;
  for(int i=0;i<chunk;i++){ int idx=b0+i; if(idx<n) s += c.cnt[idx]; }
  part[t] = s;
  __syncthreads();
  for(int off=1; off<1024; off<<=1){
    int v = (t>=off) ? part[t-off] : 0;
    __syncthreads();
    part[t] += v;
    __syncthreads();
  }
  int run = t ? part[t-1] : 0;
  for(int i=0;i<chunk;i++){
    int idx=b0+i;
    if(idx<n){ int cc = c.cnt[idx]; c.rp[idx]=run; c.cur[idx]=run; run += cc; }
  }
  if(t==0) c.rp[n] = part[1023];
}

__global__ __launch_bounds__(256) void k_fill(const int* __restrict__ eks, const int* __restrict__ ekd,
      const int* __restrict__ ses, const int* __restrict__ sed,
      int* u_eke, int* u_ekk, int* u_see, int* u_ses,
      int* o_eke, int* o_ekk, int* o_see, int* o_ses){
  int i = blockIdx.x*256 + threadIdx.x;
  if(i < NEK){
    int a = eks[i], b = ekd[i];
    int pos = atomicAdd(u_eke + a, 1);        o_eke[pos] = b;
    int pos2 = atomicAdd(u_ekk + (b-E_N), 1); o_ekk[pos2] = a;
  }
  if(i < NSE){
    int a = ses[i], b = sed[i];
    int pos = atomicAdd(u_see + a, 1);        o_see[pos] = b;
    int pos2 = atomicAdd(u_ses + (b-E_N), 1); o_ses[pos2] = a;
  }
}

// ---- split-bf16 MFMA GEMM, f32 in (convert in-register), P = exp(A·wa) epilogue ----
// block = 4 waves; wave = 32-col tile; block tile = 32 rows x 128 cols; no LDS.
#define GT0 4
#define GT1 317
#define GT2 942
#define GT3 1255
__global__ __launch_bounds__(256) void k_gemm(GS g0, GS g1, GS g2, GS g3){
  int b = blockIdx.x;
  GS g; int lt;
  if(b < GT0){ g = g0; lt = b; }
  else if(b < GT1){ g = g1; lt = b - GT0; }
  else if(b < GT2){ g = g2; lt = b - GT1; }
  else { g = g3; lt = b - GT2; }
  int l = threadIdx.x & 63, wv = threadIdx.x >> 6;
  int r0 = lt*32;
  // W fragments for this wave's 32 cols: 2 col-subtiles x 4 k-tiles, hi+lo
  bf16x8 bh[2][4], bl[2][4];
  #pragma unroll
  for(int cs=0; cs<2; cs++)
    #pragma unroll
    for(int kt=0; kt<4; kt++){
      size_t o = (((size_t)((wv*2+cs)*4 + kt))*64 + l)*8;
      bh[cs][kt] = *(const bf16x8*)(g.Wh + o);
      bl[cs][kt] = *(const bf16x8*)(g.Wl + o);
    }
  f32x4 acc[2][2];
  #pragma unroll
  for(int rs=0;rs<2;rs++)
    #pragma unroll
    for(int cs=0;cs<2;cs++) acc[rs][cs] = (f32x4){0.f,0.f,0.f,0.f};
  float pacc[2] = {0.f, 0.f};
  #pragma unroll
  for(int kt=0; kt<4; kt++){
    bf16x8 ah[2], al[2];
    #pragma unroll
    for(int rs=0; rs<2; rs++){
      int row = r0 + rs*16 + (l&15);
      float fa[8];
      if(row < g.rows){
        const float* ap = g.A + (size_t)row*128 + kt*32 + ((l>>4)<<3);
        float4 f0 = *(const float4*)ap;
        float4 f1 = *(const float4*)(ap+4);
        fa[0]=f0.x; fa[1]=f0.y; fa[2]=f0.z; fa[3]=f0.w;
        fa[4]=f1.x; fa[5]=f1.y; fa[6]=f1.z; fa[7]=f1.w;
      } else {
        #pragma unroll
        for(int j=0;j<8;j++) fa[j]=0.f;
      }
      const float* wap = g.wa + kt*32 + ((l>>4)<<3);
      float4 w0 = *(const float4*)wap;
      float4 w1 = *(const float4*)(wap+4);
      pacc[rs] += fa[0]*w0.x + fa[1]*w0.y + fa[2]*w0.z + fa[3]*w0.w
                + fa[4]*w1.x + fa[5]*w1.y + fa[6]*w1.z + fa[7]*w1.w;
      cvt8(fa, ah[rs], al[rs]);
    }
    #pragma unroll
    for(int rs=0; rs<2; rs++)
      #pragma unroll
      for(int cs=0; cs<2; cs++){
        acc[rs][cs] = __builtin_amdgcn_mfma_f32_16x16x32_bf16(ah[rs], bh[cs][kt], acc[rs][cs], 0,0,0);
        acc[rs][cs] = __builtin_amdgcn_mfma_f32_16x16x32_bf16(ah[rs], bl[cs][kt], acc[rs][cs], 0,0,0);
        acc[rs][cs] = __builtin_amdgcn_mfma_f32_16x16x32_bf16(al[rs], bh[cs][kt], acc[rs][cs], 0,0,0);
      }
  }
  // C/D layout: col = lane&15, row = (lane>>4)*4 + j   [m89-verified]
  #pragma unroll
  for(int rs=0; rs<2; rs++)
    #pragma unroll
    for(int cs=0; cs<2; cs++){
      int cb = (wv<<5) + (cs<<4) + (l&15);
      #pragma unroll
      for(int j=0;j<4;j++){
        int rr = r0 + rs*16 + ((l>>4)<<2) + j;
        if(rr < g.rows) g.Z[(size_t)rr*128 + cb] = acc[rs][cs][j];
      }
    }
  // P epilogue: reduce pacc over the 4 lane-groups sharing (l&15)
  #pragma unroll
  for(int rs=0; rs<2; rs++){
    float s = pacc[rs];
    s += __shfl_xor(s,16); s += __shfl_xor(s,32);
    int r = r0 + rs*16 + (l&15);
    if(l < 16 && r < g.rows) g.P[r] = expf(s);
  }
}

// ---- segment softmax-aggregate (p pre-exponentiated), fat-wave balanced.
// sections: [0,256) s0; [256,568) s1; [568,1193) s2 — each wave loops strided rows,
// 2 half-wave streams, float4 gathers, unroll-4. [1193,1321) s3: 1 row/block, 8 streams.
#define SGB0 256
#define SGB1 568
#define SGB2 1193
#define SGB3 1321
__global__ __launch_bounds__(256) void k_seg(SSet s0, SSet s1, SSet s2, SSet s3){
  __shared__ float4 red[4][32];
  __shared__ float redd[4];
  int b = blockIdx.x;
  int lane = threadIdx.x & 63, wid = threadIdx.x >> 6;
  int half = lane >> 5, l32 = lane & 31;
  SSet s; int wg = 0, nw = 0; bool multi = false;
  if(b < SGB0){ s = s0; wg = b*4 + wid; nw = SGB0*4; }
  else if(b < SGB1){ s = s1; wg = (b-SGB0)*4 + wid; nw = (SGB1-SGB0)*4; }
  else if(b < SGB2){ s = s2; wg = (b-SGB1)*4 + wid; nw = (SGB2-SGB1)*4; }
  else { s = s3; multi = true; }
  const int* col = s.col; const float* p = s.p; const float* z = s.z;
  if(multi){
    int row = b - SGB2;
    int e0 = s.rowptr[row], e1 = s.rowptr[row+1];
    float4 acc = {0.f,0.f,0.f,0.f}; float den = 0.f;
    int str = wid*2 + half;
    int e = e0 + str;
    for(; e + 24 < e1; e += 32){
      int cA = col[e], cB = col[e+8], cC = col[e+16], cD = col[e+24];
      float xA = p[cA], xB = p[cB], xC = p[cC], xD = p[cD];
      float4 zA = ((const float4*)(z + (size_t)cA*128))[l32];
      float4 zB = ((const float4*)(z + (size_t)cB*128))[l32];
      float4 zC = ((const float4*)(z + (size_t)cC*128))[l32];
      float4 zD = ((const float4*)(z + (size_t)cD*128))[l32];
      acc.x += xA*zA.x + xB*zB.x + xC*zC.x + xD*zD.x;
      acc.y += xA*zA.y + xB*zB.y + xC*zC.y + xD*zD.y;
      acc.z += xA*zA.z + xB*zB.z + xC*zC.z + xD*zD.z;
      acc.w += xA*zA.w + xB*zB.w + xC*zC.w + xD*zD.w;
      den += (xA + xB) + (xC + xD);
    }
    for(; e < e1; e += 8){
      int cA = col[e];
      float xA = p[cA];
      float4 zA = ((const float4*)(z + (size_t)cA*128))[l32];
      acc.x += xA*zA.x; acc.y += xA*zA.y; acc.z += xA*zA.z; acc.w += xA*zA.w;
      den += xA;
    }
    acc.x += __shfl_xor(acc.x,32); acc.y += __shfl_xor(acc.y,32);
    acc.z += __shfl_xor(acc.z,32); acc.w += __shfl_xor(acc.w,32);
    den   += __shfl_xor(den,32);
    if(half==0){ red[wid][l32] = acc; if(l32==0) redd[wid] = den; }
    __syncthreads();
    if(wid) return;
    acc = red[0][l32]; den = redd[0];
    #pragma unroll
    for(int i=1;i<4;i++){
      float4 r4 = red[i][l32];
      acc.x+=r4.x; acc.y+=r4.y; acc.z+=r4.z; acc.w+=r4.w; den += redd[i];
    }
    float inv = den > 0.f ? 1.f/den : 0.f;
    float4 res = {acc.x*inv, acc.y*inv, acc.z*inv, acc.w*inv};
    if(s.base){
      float4 b4 = ((const float4*)(s.base + (size_t)row*128))[l32];
      res.x+=b4.x; res.y+=b4.y; res.z+=b4.z; res.w+=b4.w;
    }
    if(half==0) ((float4*)(s.out + (size_t)row*128))[l32] = res;
    return;
  }
  for(int row = wg; row < s.ndst; row += nw){
    int e0 = s.rowptr[row], e1 = s.rowptr[row+1];
    float4 acc = {0.f,0.f,0.f,0.f}; float den = 0.f;
    int e = e0 + half;
    for(; e + 6 < e1; e += 8){
      int cA = col[e], cB = col[e+2], cC = col[e+4], cD = col[e+6];
      float xA = p[cA], xB = p[cB], xC = p[cC], xD = p[cD];
      float4 zA = ((const float4*)(z + (size_t)cA*128))[l32];
      float4 zB = ((const float4*)(z + (size_t)cB*128))[l32];
      float4 zC = ((const float4*)(z + (size_t)cC*128))[l32];
      float4 zD = ((const float4*)(z + (size_t)cD*128))[l32];
      acc.x += xA*zA.x + xB*zB.x + xC*zC.x + xD*zD.x;
      acc.y += xA*zA.y + xB*zB.y + xC*zC.y + xD*zD.y;
      acc.z += xA*zA.z + xB*zB.z + xC*zC.z + xD*zD.z;
      acc.w += xA*zA.w + xB*zB.w + xC*zC.w + xD*zD.w;
      den += (xA + xB) + (xC + xD);
    }
    for(; e < e1; e += 2){
      int cA = col[e];
      float xA = p[cA];
      float4 zA = ((const float4*)(z + (size_t)cA*128))[l32];
      acc.x += xA*zA.x; acc.y += xA*zA.y; acc.z += xA*zA.z; acc.w += xA*zA.w;
      den += xA;
    }
    acc.x += __shfl_xor(acc.x,32); acc.y += __shfl_xor(acc.y,32);
    acc.z += __shfl_xor(acc.z,32); acc.w += __shfl_xor(acc.w,32);
    den   += __shfl_xor(den,32);
    float inv = den > 0.f ? 1.f/den : 0.f;
    float4 res = {acc.x*inv, acc.y*inv, acc.z*inv, acc.w*inv};
    if(s.base){
      float4 b4 = ((const float4*)(s.base + (size_t)row*128))[l32];
      res.x+=b4.x; res.y+=b4.y; res.z+=b4.z; res.w+=b4.w;
    }
    if(half==0) ((float4*)(s.out + (size_t)row*128))[l32] = res;
  }
}

// ---- per-exercise gate: sc = softmax([s1,s2]); ex = base + sc0*Bx + sc1*Cx ----
__global__ __launch_bounds__(256) void k_exup(const float* __restrict__ base, float* __restrict__ ex,
     const float* __restrict__ Bx, const float* __restrict__ Cx,
     const float* __restrict__ Fw, const float* __restrict__ Fb){
  int w = (blockIdx.x*256 + threadIdx.x) >> 6;
  int lane = threadIdx.x & 63;
  if(w >= E_N) return;
  const float* er = base + (size_t)w*128;
  const float* br = Bx + (size_t)w*128;
  const float* cr = Cx + (size_t)w*128;
  float e0 = er[lane], e1 = er[lane+64];
  float b0 = br[lane], b1 = br[lane+64];
  float c0 = cr[lane], c1 = cr[lane+64];
  float s1 = e0*Fw[lane]     + e1*Fw[lane+64]
           + b0*Fw[lane+128] + b1*Fw[lane+192];
  float s2 = e0*Fw[256+lane]     + e1*Fw[256+lane+64]
           + c0*Fw[256+lane+128] + c1*Fw[256+lane+192];
  #pragma unroll
  for(int off=32; off; off>>=1){ s1 += __shfl_down(s1,off); s2 += __shfl_down(s2,off); }
  s1 = __shfl(s1, 0) + Fb[0];
  s2 = __shfl(s2, 0) + Fb[1];
  float mx = fmaxf(s1,s2);
  float pp = expf(s1-mx), qq = expf(s2-mx);
  float inv = 1.f/(pp+qq);
  float* orow = ex + (size_t)w*128;
  orow[lane]    = e0 + (pp*inv)*b0 + (qq*inv)*c0;
  orow[lane+64] = e1 + (pp*inv)*b1 + (qq*inv)*c1;
}

// ---- fused outputs ----
__global__ __launch_bounds__(256) void k_out(const float* __restrict__ st, const float* __restrict__ ex,
    const float* __restrict__ kn, const float* __restrict__ disc,
    const int* __restrict__ sid, const int* __restrict__ eid,
    float* out0, float* out1, float* out2, float* out3){
  int w = (blockIdx.x*256 + threadIdx.x) >> 6;
  int lane = threadIdx.x & 63;
  const int ROWW = 3*B_N*64;
  if(w < ROWW){
    int half = lane>>5, l32 = lane&31;
    int r = w*2 + half;
    int sec = r >> 18;              // B_N*128 = 2^18
    int rr = r & 262143;
    int b = rr >> 7, i = rr & 127;
    const float* emb; int srow; float* ob;
    if(sec==0){ emb=st; srow=sid[b]; ob=out0; }
    else if(sec==1){ emb=ex; srow=eid[b]; ob=out1; }
    else { emb=kn; srow=i; ob=out3; }
    f32x4 v = *((const f32x4*)(emb + (size_t)srow*128) + l32);
    __builtin_nontemporal_store(v, (f32x4*)(ob + (size_t)rr*128) + l32);
  } else {
    int i = (w - ROWW)*64 + lane;
    if(i < B_N) out2[i] = disc[eid[i]];
  }
}

extern "C" void kernel_launch(void* const* d_in, const int* in_sizes, int n_in,
                              void* d_out, int out_size, void* d_ws, size_t ws_size,
                              hipStream_t stream){
  (void)in_sizes; (void)out_size; (void)ws_size;
  const float* stu_emb  = (const float*)d_in[0];
  const float* exer_emb = (const float*)d_in[1];
  const float* kn_emb   = (const float*)d_in[2];
  const float* disc_emb = (const float*)d_in[3];
  const float* GW = (const float*)d_in[4];
  const float* Ga = (const float*)d_in[5];
  const float* Fw = (const float*)d_in[6];
  const float* Fb = (const float*)d_in[7];
  int base = n_in - 6;
  const int* sid    = (const int*)d_in[base];
  const int* eid    = (const int*)d_in[base+1];
  const int* ek_src = (const int*)d_in[base+2];
  const int* ek_dst = (const int*)d_in[base+3];
  const int* se_src = (const int*)d_in[base+4];
  const int* se_dst = (const int*)d_in[base+5];

  char* w = (char*)d_ws;
  size_t off = 0;
  auto alloc = [&](size_t bytes)->char*{ char* p = w + off; off += (bytes + 255) & ~(size_t)255; return p; };
  float* st_f = (float*)alloc((size_t)S_N*D_N*4);
  float* ex_f = (float*)alloc((size_t)E_N*D_N*4);
  float* kn_f = (float*)alloc((size_t)K_N*D_N*4);
  float* Bx   = (float*)alloc((size_t)E_N*D_N*4);
  float* Cx   = (float*)alloc((size_t)E_N*D_N*4);
  float* zefk = (float*)alloc((size_t)K_N*D_N*4);
  float* zkfe = (float*)alloc((size_t)E_N*D_N*4);
  float* zefu = (float*)alloc((size_t)S_N*D_N*4);
  float* zufe = (float*)alloc((size_t)E_N*D_N*4);
  float* Pefk = (float*)alloc((size_t)K_N*4);
  float* Pkfe = (float*)alloc((size_t)E_N*4);
  float* Pefu = (float*)alloc((size_t)S_N*4);
  float* Pufe = (float*)alloc((size_t)E_N*4);
  unsigned short* wf = (unsigned short*)alloc((size_t)16*16384*2);
  float* wa   = (float*)alloc((size_t)8*128*4);
  int*   cnt  = (int*)alloc((size_t)(2*E_N+K_N+S_N)*4);
  int*   rp   = (int*)alloc((size_t)(2*(E_N+1)+(K_N+1)+(S_N+1))*4);
  int*   cur  = (int*)alloc((size_t)(2*E_N+K_N+S_N)*4);
  int*   col  = (int*)alloc((size_t)(2*NEK+2*NSE)*4);

  int* cnt_eke = cnt;                 int* cnt_ekk = cnt + E_N;
  int* cnt_see = cnt + E_N + K_N;     int* cnt_ses = cnt + 2*E_N + K_N;
  int* cur_eke = cur;                 int* cur_ekk = cur + E_N;
  int* cur_see = cur + E_N + K_N;     int* cur_ses = cur + 2*E_N + K_N;
  int* rp_eke = rp;                                int* rp_ekk = rp + (E_N+1);
  int* rp_see = rp + (E_N+1) + (K_N+1);            int* rp_ses = rp + 2*(E_N+1) + (K_N+1);
  int* col_eke = col;                 int* col_ekk = col + NEK;
  int* col_see = col + 2*NEK;         int* col_ses = col + 2*NEK + NSE;

  // ---- setup: hist(+wprep) -> scan -> fill ----
  hipMemsetAsync(cnt, 0, (size_t)(2*E_N+K_N+S_N)*4, stream);
  k_hist<<<HB+8,256,0,stream>>>(ek_src, ek_dst, se_src, se_dst,
                                cnt_eke, cnt_ekk, cnt_see, cnt_ses,
                                GW, Ga, wf, wa);
  k_scan<<<4,1024,0,stream>>>(CSet{cnt_eke,E_N,rp_eke,cur_eke}, CSet{cnt_ekk,K_N,rp_ekk,cur_ekk},
                              CSet{cnt_see,E_N,rp_see,cur_see}, CSet{cnt_ses,S_N,rp_ses,cur_ses});
  k_fill<<<HB,256,0,stream>>>(ek_src, ek_dst, se_src, se_dst,
                              cur_eke, cur_ekk, cur_see, cur_ses,
                              col_eke, col_ekk, col_see, col_ses);

  for(int l=0; l<2; l++){
    const float* knp = l ? kn_f : kn_emb;
    const float* exp_ = l ? ex_f : exer_emb;
    const float* stp = l ? st_f : stu_emb;
    int l4 = l*4;
    // 4 gemms, one dispatch (f32 A, in-register bf16 split, P epilogue)
    GS g0{knp,  wf + (size_t)(l4+1)*16384, wf + (size_t)(8+l4+1)*16384, wa + (size_t)(l4+1)*128, zefk, Pefk, K_N};
    GS g1{exp_, wf + (size_t)(l4+0)*16384, wf + (size_t)(8+l4+0)*16384, wa + (size_t)(l4+0)*128, zkfe, Pkfe, E_N};
    GS g2{stp,  wf + (size_t)(l4+3)*16384, wf + (size_t)(8+l4+3)*16384, wa + (size_t)(l4+3)*128, zefu, Pefu, S_N};
    GS g3{exp_, wf + (size_t)(l4+2)*16384, wf + (size_t)(8+l4+2)*16384, wa + (size_t)(l4+2)*128, zufe, Pufe, E_N};
    k_gemm<<<GT3,256,0,stream>>>(g0,g1,g2,g3);
    // 4 aggregations, one dispatch
    SSet s0{zefk - (size_t)E_N*128, Pefk - E_N, rp_eke, col_eke, nullptr, Bx,   E_N};  // efk -> Bx
    SSet s1{zefu - (size_t)E_N*128, Pefu - E_N, rp_see, col_see, nullptr, Cx,   E_N};  // efu -> Cx
    SSet s2{zufe,                   Pufe,       rp_ses, col_ses, stp,     st_f, S_N};  // ufe -> st
    SSet s3{zkfe,                   Pkfe,       rp_ekk, col_ekk, knp,     kn_f, K_N};  // kfe -> kn
    k_seg<<<SGB3,256,0,stream>>>(s0,s1,s2,s3);
    k_exup<<<(E_N*64)/256,256,0,stream>>>(exp_, ex_f, Bx, Cx, Fw + (size_t)l*3*2*D_N, Fb + (size_t)l*3);
  }

  float* out  = (float*)d_out;
  float* out0 = out;                           // stu_ts  (B,D,D)
  float* out1 = out0 + (size_t)B_N*D_N*D_N;    // exer_ts (B,D,D)
  float* out2 = out1 + (size_t)B_N*D_N*D_N;    // disc    (B,1)
  float* out3 = out2 + (size_t)B_N;            // kn_ts   (B,K,D)
  int waves = 3*B_N*64 + 32;
  k_out<<<(waves+3)/4,256,0,stream>>>(st_f, ex_f, kn_f, disc_emb, sid, eid, out0, out1, out2, out3);
}

// Round 6
// 775.024 us; speedup vs baseline: 1.0604x; 1.0604x over previous
//
#include <hip/hip_runtime.h>

#define S_N 20000
#define E_N 10000
#define K_N 128
#define D_N 128
#define NEK 40000
#define NSE 500000
#define B_N 2048

typedef __attribute__((ext_vector_type(8))) short bf16x8;
typedef __attribute__((ext_vector_type(4))) float f32x4;

__device__ __forceinline__ unsigned short f2bf(float f){
  unsigned int u = __float_as_uint(f);
  unsigned int r = u + 0x7FFFu + ((u >> 16) & 1u);   // RNE to bf16
  return (unsigned short)(r >> 16);
}
__device__ __forceinline__ float bf2f(unsigned short h){
  return __uint_as_float(((unsigned int)h) << 16);
}

struct GS { const unsigned short* Ah; const unsigned short* Al;
            const unsigned short* Wh; const unsigned short* Wl;
            float* Z; int rows; };
struct CSet { const int* cnt; int n; int* rp; int* cur; };

// ---- hist (+ wprep piggybacked on trailing 8 blocks) ----
#define HB ((NSE+255)/256)
__global__ __launch_bounds__(256) void k_hist(const int* __restrict__ eks, const int* __restrict__ ekd,
      const int* __restrict__ ses, const int* __restrict__ sed,
      int* c_eke, int* c_ekk, int* c_see, int* c_ses,
      const float* __restrict__ GW, const float* __restrict__ Ga,
      unsigned short* __restrict__ wf, float* __restrict__ wa){
  int bb = blockIdx.x;
  if(bb >= HB){
    int g = bb - HB;                         // gate 0..7
    const float* W  = GW + (size_t)g*16384;
    const float* a1 = Ga + (size_t)g*256;    // src-half of attention vector
    unsigned short* whi = wf + (size_t)g*16384;
    unsigned short* wlo = wf + (size_t)(8+g)*16384;
    int t = threadIdx.x, l = t & 63;
    for(int pi = t>>6; pi < 32; pi += 4){
      int c2 = pi >> 2, kt = pi & 3;
      unsigned short h[8], lo[8];
      #pragma unroll
      for(int j=0;j<8;j++){
        int k = kt*32 + (l>>4)*8 + j;
        int c = c2*16 + (l&15);
        float f = W[(size_t)k*128 + c];
        unsigned short hb = f2bf(f);
        h[j] = hb; lo[j] = f2bf(f - bf2f(hb));
      }
      size_t off = ((size_t)pi*64 + l)*8;
      uint4 hv, lv;
      hv.x = (unsigned)h[0] | ((unsigned)h[1]<<16);  hv.y = (unsigned)h[2] | ((unsigned)h[3]<<16);
      hv.z = (unsigned)h[4] | ((unsigned)h[5]<<16);  hv.w = (unsigned)h[6] | ((unsigned)h[7]<<16);
      lv.x = (unsigned)lo[0] | ((unsigned)lo[1]<<16); lv.y = (unsigned)lo[2] | ((unsigned)lo[3]<<16);
      lv.z = (unsigned)lo[4] | ((unsigned)lo[5]<<16); lv.w = (unsigned)lo[6] | ((unsigned)lo[7]<<16);
      *(uint4*)(whi + off) = hv;
      *(uint4*)(wlo + off) = lv;
    }
    for(int k = t; k < 128; k += 256){       // wa[k] = sum_c W[k][c]*a1[c]
      float s = 0.f;
      const float* wr = W + (size_t)k*128;
      for(int c=0;c<128;c++) s += wr[c]*a1[c];
      wa[(size_t)g*128 + k] = s;
    }
    return;
  }
  int i = bb*256 + threadIdx.x;
  if(i < NEK){ atomicAdd(c_eke + eks[i], 1); atomicAdd(c_ekk + (ekd[i]-E_N), 1); }
  if(i < NSE){ atomicAdd(c_see + ses[i], 1); atomicAdd(c_ses + (sed[i]-E_N), 1); }
}

__global__ __launch_bounds__(1024) void k_scan(CSet c0, CSet c1, CSet c2, CSet c3){
  CSet c = c0;
  if(blockIdx.x==1) c=c1; else if(blockIdx.x==2) c=c2; else if(blockIdx.x==3) c=c3;
  __shared__ int part[1024];
  int t = threadIdx.x;
  int n = c.n;
  int chunk = (n + 1023) >> 10;
  int b0 = t * chunk;
  int s = 0;
  for(int i=0;i<chunk;i++){ int idx=b0+i; if(idx<n) s += c.cnt[idx]; }
  part[t] = s;
  __syncthreads();
  for(int off=1; off<1024; off<<=1){
    int v = (t>=off) ? part[t-off] : 0;
    __syncthreads();
    part[t] += v;
    __syncthreads();
  }
  int run = t ? part[t-1] : 0;
  for(int i=0;i<chunk;i++){
    int idx=b0+i;
    if(idx<n){ int cc = c.cnt[idx]; c.rp[idx]=run; c.cur[idx]=run; run += cc; }
  }
  if(t==0) c.rp[n] = part[1023];
}

__global__ __launch_bounds__(256) void k_fill(const int* __restrict__ eks, const int* __restrict__ ekd,
      const int* __restrict__ ses, const int* __restrict__ sed,
      int* u_eke, int* u_ekk, int* u_see, int* u_ses,
      int* o_eke, int* o_ekk, int* o_see, int* o_ses){
  int i = blockIdx.x*256 + threadIdx.x;
  if(i < NEK){
    int a = eks[i], b = ekd[i];
    int pos = atomicAdd(u_eke + a, 1);        o_eke[pos] = b;
    int pos2 = atomicAdd(u_ekk + (b-E_N), 1); o_ekk[pos2] = a;
  }
  if(i < NSE){
    int a = ses[i], b = sed[i];
    int pos = atomicAdd(u_see + a, 1);        o_see[pos] = b;
    int pos2 = atomicAdd(u_ses + (b-E_N), 1); o_ses[pos2] = a;
  }
}

// ---- per-layer state convert: f32 -> bf16 hi/lo + P = exp(h·wa) per gate ----
__global__ __launch_bounds__(256) void k_cvt(const float* __restrict__ kn, const float* __restrict__ ex,
    const float* __restrict__ st,
    unsigned short* __restrict__ knb, unsigned short* __restrict__ exb, unsigned short* __restrict__ stb,
    const float* __restrict__ wa, int l4,
    float* __restrict__ Pefk, float* __restrict__ Pkfe, float* __restrict__ Pufe, float* __restrict__ Pefu){
  int w = (blockIdx.x*256 + threadIdx.x) >> 6;
  int lane = threadIdx.x & 63;
  const float* src; unsigned short *hi, *lo; int r;
  const float* wv1; const float* wv2 = nullptr; float *P1, *P2 = nullptr;
  if(w < K_N){ r = w; src = kn + (size_t)r*128; hi = knb; lo = knb + (size_t)K_N*128;
               wv1 = wa + (size_t)(l4+1)*128; P1 = Pefk; }
  else if(w < K_N + E_N){ r = w - K_N; src = ex + (size_t)r*128; hi = exb; lo = exb + (size_t)E_N*128;
               wv1 = wa + (size_t)(l4+0)*128; P1 = Pkfe;
               wv2 = wa + (size_t)(l4+2)*128; P2 = Pufe; }
  else { r = w - K_N - E_N; if(r >= S_N) return; src = st + (size_t)r*128; hi = stb; lo = stb + (size_t)S_N*128;
               wv1 = wa + (size_t)(l4+3)*128; P1 = Pefu; }
  float2 x = ((const float2*)src)[lane];
  float2 v1 = ((const float2*)wv1)[lane];
  float d1 = x.x*v1.x + x.y*v1.y;
  float d2 = 0.f;
  if(wv2){ float2 v2 = ((const float2*)wv2)[lane]; d2 = x.x*v2.x + x.y*v2.y; }
  #pragma unroll
  for(int off=1; off<64; off<<=1){ d1 += __shfl_xor(d1,off); d2 += __shfl_xor(d2,off); }
  if(lane==0){ P1[r] = expf(d1); if(P2) P2[r] = expf(d2); }
  unsigned short h0 = f2bf(x.x), h1 = f2bf(x.y);
  unsigned short l0 = f2bf(x.x - bf2f(h0)), l1 = f2bf(x.y - bf2f(h1));
  ((ushort2*)(hi + (size_t)r*128))[lane] = make_ushort2(h0,h1);
  ((ushort2*)(lo + (size_t)r*128))[lane] = make_ushort2(l0,l1);
}

// ---- split-bf16 MFMA GEMM (bf16 hi/lo inputs; round-4 proven) ----
#define GT0 4
#define GT1 317
#define GT2 942
#define GT3 1255
__global__ __launch_bounds__(256) void k_gemm(GS g0, GS g1, GS g2, GS g3){
  int b = blockIdx.x;
  GS g; int lt;
  if(b < GT0){ g = g0; lt = b; }
  else if(b < GT1){ g = g1; lt = b - GT0; }
  else if(b < GT2){ g = g2; lt = b - GT1; }
  else { g = g3; lt = b - GT2; }
  int l = threadIdx.x & 63, wv = threadIdx.x >> 6;
  int r0 = lt*32;
  bf16x8 bh[2][4], bl[2][4];
  #pragma unroll
  for(int cs=0; cs<2; cs++)
    #pragma unroll
    for(int kt=0; kt<4; kt++){
      size_t o = (((size_t)((wv*2+cs)*4 + kt))*64 + l)*8;
      bh[cs][kt] = *(const bf16x8*)(g.Wh + o);
      bl[cs][kt] = *(const bf16x8*)(g.Wl + o);
    }
  f32x4 acc[2][2];
  #pragma unroll
  for(int rs=0;rs<2;rs++)
    #pragma unroll
    for(int cs=0;cs<2;cs++) acc[rs][cs] = (f32x4){0.f,0.f,0.f,0.f};
  #pragma unroll
  for(int kt=0; kt<4; kt++){
    bf16x8 ah[2], al[2];
    #pragma unroll
    for(int rs=0; rs<2; rs++){
      size_t ao = ((size_t)(r0 + rs*16 + (l&15)))*128 + kt*32 + (l>>4)*8;
      ah[rs] = *(const bf16x8*)(g.Ah + ao);
      al[rs] = *(const bf16x8*)(g.Al + ao);
    }
    #pragma unroll
    for(int rs=0; rs<2; rs++)
      #pragma unroll
      for(int cs=0; cs<2; cs++){
        acc[rs][cs] = __builtin_amdgcn_mfma_f32_16x16x32_bf16(ah[rs], bh[cs][kt], acc[rs][cs], 0,0,0);
        acc[rs][cs] = __builtin_amdgcn_mfma_f32_16x16x32_bf16(ah[rs], bl[cs][kt], acc[rs][cs], 0,0,0);
        acc[rs][cs] = __builtin_amdgcn_mfma_f32_16x16x32_bf16(al[rs], bh[cs][kt], acc[rs][cs], 0,0,0);
      }
  }
  // C/D layout: col = lane&15, row = (lane>>4)*4 + j
  #pragma unroll
  for(int rs=0; rs<2; rs++)
    #pragma unroll
    for(int cs=0; cs<2; cs++){
      int cb = (wv<<5) + (cs<<4) + (l&15);
      #pragma unroll
      for(int j=0;j<4;j++){
        int rr = r0 + rs*16 + ((l>>4)<<2) + j;
        if(rr < g.rows) g.Z[(size_t)rr*128 + cb] = acc[rs][cs][j];
      }
    }
}

// ---- per-row segment aggregation helper: half-wave streams, float4 gathers, unroll-4;
// result reduced across halves (both halves end with full sums) ----
__device__ __forceinline__ void seg_row(const float* __restrict__ z, const float* __restrict__ p,
                                        const int* __restrict__ col, int e0, int e1,
                                        int half, int l32, float4& accO, float& denO){
  float4 acc = {0.f,0.f,0.f,0.f}; float den = 0.f;
  int e = e0 + half;
  for(; e + 6 < e1; e += 8){
    int cA = col[e], cB = col[e+2], cC = col[e+4], cD = col[e+6];
    float xA = p[cA], xB = p[cB], xC = p[cC], xD = p[cD];
    float4 zA = ((const float4*)(z + (size_t)cA*128))[l32];
    float4 zB = ((const float4*)(z + (size_t)cB*128))[l32];
    float4 zC = ((const float4*)(z + (size_t)cC*128))[l32];
    float4 zD = ((const float4*)(z + (size_t)cD*128))[l32];
    acc.x += xA*zA.x + xB*zB.x + xC*zC.x + xD*zD.x;
    acc.y += xA*zA.y + xB*zB.y + xC*zC.y + xD*zD.y;
    acc.z += xA*zA.z + xB*zB.z + xC*zC.z + xD*zD.z;
    acc.w += xA*zA.w + xB*zB.w + xC*zC.w + xD*zD.w;
    den += (xA + xB) + (xC + xD);
  }
  for(; e < e1; e += 2){
    int cA = col[e];
    float xA = p[cA];
    float4 zA = ((const float4*)(z + (size_t)cA*128))[l32];
    acc.x += xA*zA.x; acc.y += xA*zA.y; acc.z += xA*zA.z; acc.w += xA*zA.w;
    den += xA;
  }
  acc.x += __shfl_xor(acc.x,32); acc.y += __shfl_xor(acc.y,32);
  acc.z += __shfl_xor(acc.z,32); acc.w += __shfl_xor(acc.w,32);
  den   += __shfl_xor(den,32);
  accO = acc; denO = den;
}

// ---- fused segment + gate kernel. Flattened grid:
// [0,2500): ex rows — aggregate ek(Bx) + se(Cx) in regs, softmax gate, write ex_f.
// [2500,7500): st rows — aggregate ses + base -> st_f.
// [7500,7628): kn rows — multi-wave (8 streams), + base -> kn_f.
#define S2A 2500
#define S2B 7500
#define S2C 7628
__global__ __launch_bounds__(256) void k_seg2(
    const float* __restrict__ zB, const float* __restrict__ pB, const int* __restrict__ rpB, const int* __restrict__ colB,
    const float* __restrict__ zC, const float* __restrict__ pC, const int* __restrict__ rpC, const int* __restrict__ colC,
    const float* __restrict__ zS, const float* __restrict__ pS, const int* __restrict__ rpS, const int* __restrict__ colS,
    const float* __restrict__ stBase, float* __restrict__ stOut,
    const float* __restrict__ zK, const float* __restrict__ pK, const int* __restrict__ rpK, const int* __restrict__ colK,
    const float* __restrict__ knBase, float* __restrict__ knOut,
    const float* __restrict__ exBase, float* __restrict__ exOut,
    const float* __restrict__ Fwl, const float* __restrict__ Fbl){
  __shared__ float4 red[4][32];
  __shared__ float redd[4];
  int b = blockIdx.x;
  int lane = threadIdx.x & 63, wid = threadIdx.x >> 6;
  int half = lane >> 5, l32 = lane & 31;
  if(b < S2A){
    int row = b*4 + wid;                     // ex row, < 10000
    float4 accB; float denB;
    seg_row(zB, pB, colB, rpB[row], rpB[row+1], half, l32, accB, denB);
    float4 accC; float denC;
    seg_row(zC, pC, colC, rpC[row], rpC[row+1], half, l32, accC, denC);
    float invB = denB > 0.f ? 1.f/denB : 0.f;
    float invC = denC > 0.f ? 1.f/denC : 0.f;
    float4 Bx4 = {accB.x*invB, accB.y*invB, accB.z*invB, accB.w*invB};
    float4 Cx4 = {accC.x*invC, accC.y*invC, accC.z*invC, accC.w*invC};
    float4 ex4 = ((const float4*)(exBase + (size_t)row*128))[l32];
    float4 fa = *(const float4*)(Fwl + 4*l32);
    float4 fb = *(const float4*)(Fwl + 128 + 4*l32);
    float4 fc = *(const float4*)(Fwl + 256 + 4*l32);
    float4 fd = *(const float4*)(Fwl + 384 + 4*l32);
    float s1 = ex4.x*fa.x + ex4.y*fa.y + ex4.z*fa.z + ex4.w*fa.w
             + Bx4.x*fb.x + Bx4.y*fb.y + Bx4.z*fb.z + Bx4.w*fb.w;
    float s2 = ex4.x*fc.x + ex4.y*fc.y + ex4.z*fc.z + ex4.w*fc.w
             + Cx4.x*fd.x + Cx4.y*fd.y + Cx4.z*fd.z + Cx4.w*fd.w;
    #pragma unroll
    for(int off=1; off<32; off<<=1){ s1 += __shfl_xor(s1,off); s2 += __shfl_xor(s2,off); }
    s1 += Fbl[0]; s2 += Fbl[1];
    float mx = fmaxf(s1,s2);
    float pp = expf(s1-mx), qq = expf(s2-mx);
    float iv = 1.f/(pp+qq);
    pp *= iv; qq *= iv;
    float4 o = {ex4.x + pp*Bx4.x + qq*Cx4.x, ex4.y + pp*Bx4.y + qq*Cx4.y,
                ex4.z + pp*Bx4.z + qq*Cx4.z, ex4.w + pp*Bx4.w + qq*Cx4.w};
    if(half==0) ((float4*)(exOut + (size_t)row*128))[l32] = o;
  } else if(b < S2B){
    int row = (b-S2A)*4 + wid;               // st row, < 20000
    float4 acc; float den;
    seg_row(zS, pS, colS, rpS[row], rpS[row+1], half, l32, acc, den);
    float inv = den > 0.f ? 1.f/den : 0.f;
    float4 b4 = ((const float4*)(stBase + (size_t)row*128))[l32];
    float4 res = {acc.x*inv + b4.x, acc.y*inv + b4.y, acc.z*inv + b4.z, acc.w*inv + b4.w};
    if(half==0) ((float4*)(stOut + (size_t)row*128))[l32] = res;
  } else {
    int row = b - S2B;                       // kn row, < 128, 4 waves = 8 streams
    int e0 = rpK[row], e1 = rpK[row+1];
    float4 acc = {0.f,0.f,0.f,0.f}; float den = 0.f;
    int str = wid*2 + half;
    int e = e0 + str;
    for(; e + 24 < e1; e += 32){
      int cA = colK[e], cB = colK[e+8], cC = colK[e+16], cD = colK[e+24];
      float xA = pK[cA], xB = pK[cB], xC = pK[cC], xD = pK[cD];
      float4 zA = ((const float4*)(zK + (size_t)cA*128))[l32];
      float4 zB4 = ((const float4*)(zK + (size_t)cB*128))[l32];
      float4 zC4 = ((const float4*)(zK + (size_t)cC*128))[l32];
      float4 zD4 = ((const float4*)(zK + (size_t)cD*128))[l32];
      acc.x += xA*zA.x + xB*zB4.x + xC*zC4.x + xD*zD4.x;
      acc.y += xA*zA.y + xB*zB4.y + xC*zC4.y + xD*zD4.y;
      acc.z += xA*zA.z + xB*zB4.z + xC*zC4.z + xD*zD4.z;
      acc.w += xA*zA.w + xB*zB4.w + xC*zC4.w + xD*zD4.w;
      den += (xA + xB) + (xC + xD);
    }
    for(; e < e1; e += 8){
      int cA = colK[e];
      float xA = pK[cA];
      float4 zA = ((const float4*)(zK + (size_t)cA*128))[l32];
      acc.x += xA*zA.x; acc.y += xA*zA.y; acc.z += xA*zA.z; acc.w += xA*zA.w;
      den += xA;
    }
    acc.x += __shfl_xor(acc.x,32); acc.y += __shfl_xor(acc.y,32);
    acc.z += __shfl_xor(acc.z,32); acc.w += __shfl_xor(acc.w,32);
    den   += __shfl_xor(den,32);
    if(half==0){ red[wid][l32] = acc; if(l32==0) redd[wid] = den; }
    __syncthreads();
    if(wid) return;
    acc = red[0][l32]; den = redd[0];
    #pragma unroll
    for(int i=1;i<4;i++){
      float4 r4 = red[i][l32];
      acc.x+=r4.x; acc.y+=r4.y; acc.z+=r4.z; acc.w+=r4.w; den += redd[i];
    }
    float inv = den > 0.f ? 1.f/den : 0.f;
    float4 b4 = ((const float4*)(knBase + (size_t)row*128))[l32];
    float4 res = {acc.x*inv + b4.x, acc.y*inv + b4.y, acc.z*inv + b4.z, acc.w*inv + b4.w};
    if(half==0) ((float4*)(knOut + (size_t)row*128))[l32] = res;
  }
}

// ---- fused outputs ----
__global__ __launch_bounds__(256) void k_out(const float* __restrict__ st, const float* __restrict__ ex,
    const float* __restrict__ kn, const float* __restrict__ disc,
    const int* __restrict__ sid, const int* __restrict__ eid,
    float* out0, float* out1, float* out2, float* out3){
  int w = (blockIdx.x*256 + threadIdx.x) >> 6;
  int lane = threadIdx.x & 63;
  const int ROWW = 3*B_N*64;
  if(w < ROWW){
    int half = lane>>5, l32 = lane&31;
    int r = w*2 + half;
    int sec = r >> 18;              // B_N*128 = 2^18
    int rr = r & 262143;
    int b = rr >> 7, i = rr & 127;
    const float* emb; int srow; float* ob;
    if(sec==0){ emb=st; srow=sid[b]; ob=out0; }
    else if(sec==1){ emb=ex; srow=eid[b]; ob=out1; }
    else { emb=kn; srow=i; ob=out3; }
    f32x4 v = *((const f32x4*)(emb + (size_t)srow*128) + l32);
    __builtin_nontemporal_store(v, (f32x4*)(ob + (size_t)rr*128) + l32);
  } else {
    int i = (w - ROWW)*64 + lane;
    if(i < B_N) out2[i] = disc[eid[i]];
  }
}

extern "C" void kernel_launch(void* const* d_in, const int* in_sizes, int n_in,
                              void* d_out, int out_size, void* d_ws, size_t ws_size,
                              hipStream_t stream){
  (void)in_sizes; (void)out_size; (void)ws_size;
  const float* stu_emb  = (const float*)d_in[0];
  const float* exer_emb = (const float*)d_in[1];
  const float* kn_emb   = (const float*)d_in[2];
  const float* disc_emb = (const float*)d_in[3];
  const float* GW = (const float*)d_in[4];
  const float* Ga = (const float*)d_in[5];
  const float* Fw = (const float*)d_in[6];
  const float* Fb = (const float*)d_in[7];
  int base = n_in - 6;
  const int* sid    = (const int*)d_in[base];
  const int* eid    = (const int*)d_in[base+1];
  const int* ek_src = (const int*)d_in[base+2];
  const int* ek_dst = (const int*)d_in[base+3];
  const int* se_src = (const int*)d_in[base+4];
  const int* se_dst = (const int*)d_in[base+5];

  char* w = (char*)d_ws;
  size_t off = 0;
  auto alloc = [&](size_t bytes)->char*{ char* p = w + off; off += (bytes + 255) & ~(size_t)255; return p; };
  float* st_f = (float*)alloc((size_t)S_N*D_N*4);
  float* ex_f = (float*)alloc((size_t)E_N*D_N*4);
  float* kn_f = (float*)alloc((size_t)K_N*D_N*4);
  float* zefk = (float*)alloc((size_t)K_N*D_N*4);
  float* zkfe = (float*)alloc((size_t)E_N*D_N*4);
  float* zefu = (float*)alloc((size_t)S_N*D_N*4);
  float* zufe = (float*)alloc((size_t)E_N*D_N*4);
  float* Pefk = (float*)alloc((size_t)K_N*4);
  float* Pkfe = (float*)alloc((size_t)E_N*4);
  float* Pefu = (float*)alloc((size_t)S_N*4);
  float* Pufe = (float*)alloc((size_t)E_N*4);
  unsigned short* knb = (unsigned short*)alloc((size_t)K_N*D_N*2*2 + 4096);
  unsigned short* exb = (unsigned short*)alloc((size_t)E_N*D_N*2*2 + 4096);
  unsigned short* stb = (unsigned short*)alloc((size_t)S_N*D_N*2*2 + 4096);
  unsigned short* wf  = (unsigned short*)alloc((size_t)16*16384*2);
  float* wa   = (float*)alloc((size_t)8*128*4);
  int*   cnt  = (int*)alloc((size_t)(2*E_N+K_N+S_N)*4);
  int*   rp   = (int*)alloc((size_t)(2*(E_N+1)+(K_N+1)+(S_N+1))*4);
  int*   cur  = (int*)alloc((size_t)(2*E_N+K_N+S_N)*4);
  int*   col  = (int*)alloc((size_t)(2*NEK+2*NSE)*4);

  int* cnt_eke = cnt;                 int* cnt_ekk = cnt + E_N;
  int* cnt_see = cnt + E_N + K_N;     int* cnt_ses = cnt + 2*E_N + K_N;
  int* cur_eke = cur;                 int* cur_ekk = cur + E_N;
  int* cur_see = cur + E_N + K_N;     int* cur_ses = cur + 2*E_N + K_N;
  int* rp_eke = rp;                                int* rp_ekk = rp + (E_N+1);
  int* rp_see = rp + (E_N+1) + (K_N+1);            int* rp_ses = rp + 2*(E_N+1) + (K_N+1);
  int* col_eke = col;                 int* col_ekk = col + NEK;
  int* col_see = col + 2*NEK;         int* col_ses = col + 2*NEK + NSE;

  // ---- setup: hist(+wprep) -> scan -> fill ----
  hipMemsetAsync(cnt, 0, (size_t)(2*E_N+K_N+S_N)*4, stream);
  k_hist<<<HB+8,256,0,stream>>>(ek_src, ek_dst, se_src, se_dst,
                                cnt_eke, cnt_ekk, cnt_see, cnt_ses,
                                GW, Ga, wf, wa);
  k_scan<<<4,1024,0,stream>>>(CSet{cnt_eke,E_N,rp_eke,cur_eke}, CSet{cnt_ekk,K_N,rp_ekk,cur_ekk},
                              CSet{cnt_see,E_N,rp_see,cur_see}, CSet{cnt_ses,S_N,rp_ses,cur_ses});
  k_fill<<<HB,256,0,stream>>>(ek_src, ek_dst, se_src, se_dst,
                              cur_eke, cur_ekk, cur_see, cur_ses,
                              col_eke, col_ekk, col_see, col_ses);

  const unsigned short* knb_lo = knb + (size_t)K_N*128;
  const unsigned short* exb_lo = exb + (size_t)E_N*128;
  const unsigned short* stb_lo = stb + (size_t)S_N*128;

  for(int l=0; l<2; l++){
    const float* knp = l ? kn_f : kn_emb;
    const float* exp_ = l ? ex_f : exer_emb;
    const float* stp = l ? st_f : stu_emb;
    int l4 = l*4;
    // state -> bf16 hi/lo + pre-exp'd attention scores (once per element)
    k_cvt<<<(K_N+E_N+S_N)/4,256,0,stream>>>(knp, exp_, stp, knb, exb, stb, wa, l4,
                                            Pefk, Pkfe, Pufe, Pefu);
    // 4 gemms, one dispatch: gates (l4+1: kn), (l4+0: ex), (l4+3: st), (l4+2: ex)
    GS g0{knb, knb_lo, wf + (size_t)(l4+1)*16384, wf + (size_t)(8+l4+1)*16384, zefk, K_N};
    GS g1{exb, exb_lo, wf + (size_t)(l4+0)*16384, wf + (size_t)(8+l4+0)*16384, zkfe, E_N};
    GS g2{stb, stb_lo, wf + (size_t)(l4+3)*16384, wf + (size_t)(8+l4+3)*16384, zefu, S_N};
    GS g3{exb, exb_lo, wf + (size_t)(l4+2)*16384, wf + (size_t)(8+l4+2)*16384, zufe, E_N};
    k_gemm<<<GT3,256,0,stream>>>(g0,g1,g2,g3);
    // fused aggregations + ex gate, one dispatch
    k_seg2<<<S2C,256,0,stream>>>(
      zefk - (size_t)E_N*128, Pefk - E_N, rp_eke, col_eke,     // efk (ek by ex) -> Bx regs
      zefu - (size_t)E_N*128, Pefu - E_N, rp_see, col_see,     // efu (se by ex) -> Cx regs
      zufe, Pufe, rp_ses, col_ses, stp, st_f,                  // ufe -> st_f
      zkfe, Pkfe, rp_ekk, col_ekk, knp, kn_f,                  // kfe -> kn_f
      exp_, ex_f, Fw + (size_t)l*3*2*D_N, Fb + (size_t)l*3);   // gate
  }

  float* out  = (float*)d_out;
  float* out0 = out;                           // stu_ts  (B,D,D)
  float* out1 = out0 + (size_t)B_N*D_N*D_N;    // exer_ts (B,D,D)
  float* out2 = out1 + (size_t)B_N*D_N*D_N;    // disc    (B,1)
  float* out3 = out2 + (size_t)B_N;            // kn_ts   (B,K,D)
  int waves = 3*B_N*64 + 32;
  k_out<<<(waves+3)/4,256,0,stream>>>(st_f, ex_f, kn_f, disc_emb, sid, eid, out0, out1, out2, out3);
}